// Round 1
// baseline (8261.928 us; speedup 1.0000x reference)
//
#include <hip/hip_runtime.h>
#include <math.h>

#define SQRT8_INV  0.35355339059327373f   // 1/sqrt(8)
#define H_SCALE    0.04419417382415922f   // 0.25/sqrt(32)  (alpha/sqrt(32))
#define FAN_SC     0.04419417382415922f   // 1/sqrt(32*16)
#define W1_SCALE   0.125f                 // 1/sqrt(64)
#define LIN2_SCALE 0.125f                 // 1/sqrt(64)
#define SQ3_INVF   0.57735026918962576f   // 1/sqrt(3)

// ---------------- zero scratch (mn accumulator) ----------------
__global__ __launch_bounds__(256) void zero_kernel(float4* __restrict__ p, int n4) {
    int i = blockIdx.x * 256 + threadIdx.x;
    if (i < n4) p[i] = make_float4(0.f, 0.f, 0.f, 0.f);
}

// ---------------- transpose mlp_w1 (64,128) -> w1x[c][j][4] ----------------
// w1x[(c*64 + j)*4 + q] = w1[j*128 + q*32 + c]
__global__ __launch_bounds__(256) void prep_w1x(const float* __restrict__ w1,
                                                float* __restrict__ w1x) {
    int idx = blockIdx.x * 256 + threadIdx.x;   // 0 .. 8191
    if (idx >= 128 * 64) return;
    int c = idx >> 6, j = idx & 63;
    #pragma unroll
    for (int q = 0; q < 4; ++q)
        w1x[(idx << 2) + q] = w1[j * 128 + q * 32 + c];
}

// ---------------- node stage: h (lin1) + sc into d_out ----------------
// h layout: h4[n*128 + c*4 + 0] = h0[c]; +1+m = h1[c][m]
__global__ __launch_bounds__(128) void node_kernel(
    const float* __restrict__ nf, const float* __restrict__ attrs,
    const float* __restrict__ l1w0, const float* __restrict__ l1w1,
    const float* __restrict__ scw0, const float* __restrict__ scw1,
    float* __restrict__ h4, float* __restrict__ out) {
    int n = blockIdx.x;
    int t = threadIdx.x;
    __shared__ float x[128];
    __shared__ int vs;
    x[t] = nf[n * 128 + t];
    if (t < 16) {
        if (attrs[n * 16 + t] > 0.5f) vs = t;   // one-hot: exactly one writer
    }
    __syncthreads();
    int v = vs;
    if (t < 32) {
        int w = t;
        float a = 0.f, b = 0.f;
        #pragma unroll
        for (int u = 0; u < 32; ++u) {
            float xv = x[u];
            a = fmaf(xv, l1w0[u * 32 + w], a);
            b = fmaf(xv, scw0[u * 512 + v * 32 + w], b);
        }
        h4[n * 128 + w * 4] = a * H_SCALE;
        out[n * 128 + w]    = b * FAN_SC;
    } else {
        int j = t - 32;                // 0..95
        int vch = j / 3, m = j - vch * 3;
        float a = 0.f, b = 0.f;
        #pragma unroll
        for (int u = 0; u < 32; ++u) {
            float xv = x[32 + u * 3 + m];
            a = fmaf(xv, l1w1[u * 32 + vch], a);
            b = fmaf(xv, scw1[u * 512 + v * 32 + vch], b);
        }
        h4[n * 128 + vch * 4 + 1 + m]  = a * H_SCALE;
        out[n * 128 + 32 + vch * 3 + m] = b * FAN_SC;
    }
}

// ---------------- edge stage: MLP + messages + atomic scatter ----------------
__global__ __launch_bounds__(256) void edge_kernel(
    const float* __restrict__ ee, const float* __restrict__ eattr,
    const int* __restrict__ eidx,
    const float* __restrict__ w0, const float* __restrict__ w1x,
    const float4* __restrict__ h4, float* __restrict__ mn, int E) {
    int e = blockIdx.x * 256 + threadIdx.x;
    if (e >= E) return;
    int dst = eidx[e];
    int src = eidx[E + e];

    // load + pre-scale edge embedding (8 floats)
    const float4* eep = (const float4*)ee;
    float4 e0 = eep[e * 2], e1 = eep[e * 2 + 1];
    float eev[8];
    eev[0] = e0.x * SQRT8_INV; eev[1] = e0.y * SQRT8_INV;
    eev[2] = e0.z * SQRT8_INV; eev[3] = e0.w * SQRT8_INV;
    eev[4] = e1.x * SQRT8_INV; eev[5] = e1.y * SQRT8_INV;
    eev[6] = e1.z * SQRT8_INV; eev[7] = e1.w * SQRT8_INV;

    // layer 1 + silu (weights wave-uniform -> s_load)
    float hid[64];
    #pragma unroll
    for (int j = 0; j < 64; ++j) {
        float a = 0.f;
        #pragma unroll
        for (int k = 0; k < 8; ++k) a = fmaf(eev[k], w0[k * 64 + j], a);
        float s = 1.f / (1.f + __expf(-a));
        hid[j] = a * s * W1_SCALE;      // fold 1/sqrt(64) of layer 2 here
    }

    float4 ea = ((const float4*)eattr)[e];
    float y0 = ea.x;
    float y1x = ea.y, y1y = ea.z, y1z = ea.w;

    float* mrow = mn + (size_t)dst * 256;
    const float4* hrow = h4 + (size_t)src * 32;

    for (int c = 0; c < 32; ++c) {
        const float* wp = w1x + c * 256;  // uniform -> s_load stream
        float wa = 0.f, wb = 0.f, wc_ = 0.f, wd = 0.f;
        #pragma unroll
        for (int j = 0; j < 64; ++j) {
            float hj = hid[j];
            wa  = fmaf(hj, wp[j * 4 + 0], wa);
            wb  = fmaf(hj, wp[j * 4 + 1], wb);
            wc_ = fmaf(hj, wp[j * 4 + 2], wc_);
            wd  = fmaf(hj, wp[j * 4 + 3], wd);
        }
        float4 xs = hrow[c];   // {h0[c], h1[c][0..2]} of src node
        float m0a = wa * xs.x * y0;
        float dv  = xs.y * y1x + xs.z * y1y + xs.w * y1z;
        float m0b = wd * dv * SQ3_INVF;
        atomicAdd(mrow + c,      m0a);
        atomicAdd(mrow + 32 + c, m0b);
        float bx = wb * xs.x;
        atomicAdd(mrow + 64 + c * 3 + 0, bx * y1x);
        atomicAdd(mrow + 64 + c * 3 + 1, bx * y1y);
        atomicAdd(mrow + 64 + c * 3 + 2, bx * y1z);
        float cy = wc_ * y0;
        atomicAdd(mrow + 160 + c * 3 + 0, cy * xs.y);
        atomicAdd(mrow + 160 + c * 3 + 1, cy * xs.z);
        atomicAdd(mrow + 160 + c * 3 + 2, cy * xs.w);
    }
}

// ---------------- output stage: lin2(mn) + sc (already in out) ----------------
__global__ __launch_bounds__(128) void out_kernel(
    const float* __restrict__ mn, const float* __restrict__ l2w0,
    const float* __restrict__ l2w1, float* __restrict__ out) {
    int n = blockIdx.x, t = threadIdx.x;
    __shared__ float ld[256];
    ld[t]       = mn[(size_t)n * 256 + t];
    ld[t + 128] = mn[(size_t)n * 256 + t + 128];
    __syncthreads();
    float acc = 0.f;
    if (t < 32) {
        #pragma unroll
        for (int u = 0; u < 64; ++u)
            acc = fmaf(ld[u], l2w0[u * 32 + t], acc);
        out[(size_t)n * 128 + t] += acc * LIN2_SCALE;
    } else {
        int j = t - 32;
        int vch = j / 3, m = j - vch * 3;
        #pragma unroll
        for (int u = 0; u < 64; ++u)
            acc = fmaf(ld[64 + u * 3 + m], l2w1[u * 32 + vch], acc);
        out[(size_t)n * 128 + t] += acc * LIN2_SCALE;
    }
}

extern "C" void kernel_launch(void* const* d_in, const int* in_sizes, int n_in,
                              void* d_out, int out_size, void* d_ws, size_t ws_size,
                              hipStream_t stream) {
    const float* nf    = (const float*)d_in[0];
    const float* attrs = (const float*)d_in[1];
    const float* eattr = (const float*)d_in[2];
    const float* ee    = (const float*)d_in[3];
    const int*   eidx  = (const int*)d_in[4];
    const float* l1w0  = (const float*)d_in[5];
    const float* l1w1  = (const float*)d_in[6];
    const float* w0    = (const float*)d_in[7];
    const float* w1    = (const float*)d_in[8];
    const float* l2w0  = (const float*)d_in[9];
    const float* l2w1  = (const float*)d_in[10];
    const float* scw0  = (const float*)d_in[11];
    const float* scw1  = (const float*)d_in[12];

    int N = in_sizes[0] / 128;
    int E = in_sizes[3] / 8;

    float* h4  = (float*)d_ws;                       // N*128 floats
    float* mn  = h4 + (size_t)N * 128;               // N*256 floats
    float* w1x = mn + (size_t)N * 256;               // 8192*4 floats

    int mn4 = N * 64;   // float4 count of mn
    zero_kernel<<<(mn4 + 255) / 256, 256, 0, stream>>>((float4*)mn, mn4);
    prep_w1x<<<32, 256, 0, stream>>>(w1, w1x);
    node_kernel<<<N, 128, 0, stream>>>(nf, attrs, l1w0, l1w1, scw0, scw1, h4, (float*)d_out);
    edge_kernel<<<(E + 255) / 256, 256, 0, stream>>>(ee, eattr, eidx, w0, w1x,
                                                     (const float4*)h4, mn, E);
    out_kernel<<<N, 128, 0, stream>>>(mn, l2w0, l2w1, (float*)d_out);
}

// Round 2
// 638.977 us; speedup vs baseline: 12.9299x; 12.9299x over previous
//
#include <hip/hip_runtime.h>
#include <math.h>

#define SQRT8_INV  0.35355339059327373f   // 1/sqrt(8)
#define H_SCALE    0.04419417382415922f   // 0.25/sqrt(32)
#define FAN_SC     0.04419417382415922f   // 1/sqrt(32*16)
#define W1_SCALE   0.125f                 // 1/sqrt(64)
#define LIN2_SCALE 0.125f                 // 1/sqrt(64)
#define SQ3_INVF   0.57735026918962576f   // 1/sqrt(3)

// ---------------- zero int buffer ----------------
__global__ __launch_bounds__(256) void zero_int(int* __restrict__ p, int n) {
    int i = blockIdx.x * 256 + threadIdx.x;
    if (i < n) p[i] = 0;
}

// ---------------- interleave mlp_w1 columns per gather-thread ----------------
// thread t needs cols: t<32 -> (t, t+32) = (wa,wb);  t>=32 -> (t+32, t+64) = (wc,wd)
// w1p[(j*64+t)*2 + {0,1}] = w1[j*128 + {colA,colB}]
__global__ __launch_bounds__(256) void prep_w1p(const float* __restrict__ w1,
                                                float* __restrict__ w1p) {
    int idx = blockIdx.x * 256 + threadIdx.x;
    if (idx >= 64 * 64) return;
    int j = idx >> 6, t = idx & 63;
    int colA = (t < 32) ? t : t + 32;
    int colB = (t < 32) ? t + 32 : t + 64;
    w1p[idx * 2 + 0] = w1[j * 128 + colA];
    w1p[idx * 2 + 1] = w1[j * 128 + colB];
}

// ---------------- histogram of edge_dst ----------------
__global__ __launch_bounds__(256) void hist_kernel(const int* __restrict__ eidx,
                                                   int* __restrict__ cnt, int E) {
    int e = blockIdx.x * 256 + threadIdx.x;
    if (e < E) atomicAdd(&cnt[eidx[e]], 1);
}

// ---------------- exclusive scan of counts (single block) ----------------
__global__ __launch_bounds__(1024) void scan_kernel(const int* __restrict__ cnt,
                                                    int* __restrict__ off,
                                                    int* __restrict__ cur, int N) {
    __shared__ int sums[1024];
    int t = threadIdx.x;
    int chunk = (N + 1023) >> 10;
    int lo = t * chunk, hi = min(lo + chunk, N);
    int s = 0;
    for (int i = lo; i < hi; ++i) s += cnt[i];
    sums[t] = s;
    __syncthreads();
    for (int d = 1; d < 1024; d <<= 1) {
        int v = (t >= d) ? sums[t - d] : 0;
        __syncthreads();
        sums[t] += v;
        __syncthreads();
    }
    int base = (t == 0) ? 0 : sums[t - 1];
    for (int i = lo; i < hi; ++i) { off[i] = base; cur[i] = base; base += cnt[i]; }
    if (t == 1023) off[N] = sums[1023];
}

// ---------------- scatter edge ids into dst-sorted order ----------------
__global__ __launch_bounds__(256) void scatter_kernel(const int* __restrict__ eidx,
                                                      int* __restrict__ cur,
                                                      int* __restrict__ order, int E) {
    int e = blockIdx.x * 256 + threadIdx.x;
    if (e >= E) return;
    int pos = atomicAdd(&cur[eidx[e]], 1);
    order[pos] = e;
}

// ---------------- node stage: h (lin1, interleaved float4) + sc into out ----------------
__global__ __launch_bounds__(128) void node_kernel(
    const float* __restrict__ nf, const float* __restrict__ attrs,
    const float* __restrict__ l1w0, const float* __restrict__ l1w1,
    const float* __restrict__ scw0, const float* __restrict__ scw1,
    float* __restrict__ h4, float* __restrict__ out) {
    int n = blockIdx.x;
    int t = threadIdx.x;
    __shared__ float x[128];
    __shared__ int vs;
    x[t] = nf[n * 128 + t];
    if (t < 16) {
        if (attrs[n * 16 + t] > 0.5f) vs = t;   // one-hot: exactly one writer
    }
    __syncthreads();
    int v = vs;
    if (t < 32) {
        int w = t;
        float a = 0.f, b = 0.f;
        #pragma unroll
        for (int u = 0; u < 32; ++u) {
            float xv = x[u];
            a = fmaf(xv, l1w0[u * 32 + w], a);
            b = fmaf(xv, scw0[u * 512 + v * 32 + w], b);
        }
        h4[n * 128 + w * 4] = a * H_SCALE;
        out[n * 128 + w]    = b * FAN_SC;
    } else {
        int j = t - 32;                // 0..95
        int vch = j / 3, m = j - vch * 3;
        float a = 0.f, b = 0.f;
        #pragma unroll
        for (int u = 0; u < 32; ++u) {
            float xv = x[32 + u * 3 + m];
            a = fmaf(xv, l1w1[u * 32 + vch], a);
            b = fmaf(xv, scw1[u * 512 + v * 32 + vch], b);
        }
        h4[n * 128 + vch * 4 + 1 + m]   = a * H_SCALE;
        out[n * 128 + 32 + vch * 3 + m] = b * FAN_SC;
    }
}

// ---------------- gather: per-dst-node edge loop, MLP recomputed cooperatively,
//                  message accumulate in regs, fused lin2 epilogue ----------------
__global__ __launch_bounds__(64) void gather_kernel(
    const float* __restrict__ ee, const float4* __restrict__ eattr4,
    const int* __restrict__ eidx, const int* __restrict__ order,
    const int* __restrict__ off,
    const float* __restrict__ w0, const float2* __restrict__ w1p2,
    const float4* __restrict__ h4,
    const float* __restrict__ l2w0, const float* __restrict__ l2w1,
    float* __restrict__ out, int E) {
    int n = blockIdx.x, t = threadIdx.x;
    int beg = off[n], end = off[n + 1];
    __shared__ float s_ee[8];
    __shared__ float s_hid[64];
    __shared__ float ld[256];
    float acc0 = 0.f, acc1 = 0.f, acc2 = 0.f, acc3 = 0.f;
    int c = t & 31;

    for (int i = beg; i < end; ++i) {
        int e = order[i];
        int src = eidx[E + e];
        if (t < 8) s_ee[t] = ee[e * 8 + t] * SQRT8_INV;
        __syncthreads();
        float a = 0.f;
        #pragma unroll
        for (int k = 0; k < 8; ++k) a = fmaf(s_ee[k], w0[k * 64 + t], a);
        float sg = 1.f / (1.f + __expf(-a));
        __syncthreads();
        s_hid[t] = a * sg * W1_SCALE;
        __syncthreads();
        float wA = 0.f, wB = 0.f;
        #pragma unroll
        for (int j = 0; j < 64; ++j) {
            float2 wv = w1p2[j * 64 + t];
            float hj = s_hid[j];
            wA = fmaf(hj, wv.x, wA);
            wB = fmaf(hj, wv.y, wB);
        }
        float4 xs = h4[(size_t)src * 32 + c];
        float4 ea = eattr4[e];
        if (t < 32) {
            // wA=wa[c], wB=wb[c]
            acc0 = fmaf(wA * xs.x, ea.x, acc0);          // m0a
            float bx = wB * xs.x;
            acc1 = fmaf(bx, ea.y, acc1);                 // m1a[*]
            acc2 = fmaf(bx, ea.z, acc2);
            acc3 = fmaf(bx, ea.w, acc3);
        } else {
            // wA=wc[c], wB=wd[c]
            float dv = xs.y * ea.y + xs.z * ea.z + xs.w * ea.w;
            acc0 = fmaf(wB * SQ3_INVF, dv, acc0);        // m0b
            float cy = wA * ea.x;
            acc1 = fmaf(cy, xs.y, acc1);                 // m1b[*]
            acc2 = fmaf(cy, xs.z, acc2);
            acc3 = fmaf(cy, xs.w, acc3);
        }
    }

    // deposit mn row into LDS: [0:32]=m0a, [32:64]=m0b, [64:160]=m1a, [160:256]=m1b
    if (t < 32) {
        ld[t] = acc0;
        ld[64 + t * 3 + 0] = acc1;
        ld[64 + t * 3 + 1] = acc2;
        ld[64 + t * 3 + 2] = acc3;
    } else {
        int cc = t - 32;
        ld[32 + cc] = acc0;
        ld[160 + cc * 3 + 0] = acc1;
        ld[160 + cc * 3 + 1] = acc2;
        ld[160 + cc * 3 + 2] = acc3;
    }
    __syncthreads();

    // fused lin2: two outputs per thread (j = t, j = t+64); sc already in out
    #pragma unroll
    for (int half = 0; half < 2; ++half) {
        int j = t + half * 64;
        float acc = 0.f;
        if (j < 32) {
            #pragma unroll
            for (int u = 0; u < 64; ++u) acc = fmaf(ld[u], l2w0[u * 32 + j], acc);
        } else {
            int jj = j - 32, vch = jj / 3, m = jj - vch * 3;
            #pragma unroll
            for (int u = 0; u < 64; ++u) acc = fmaf(ld[64 + u * 3 + m], l2w1[u * 32 + vch], acc);
        }
        out[(size_t)n * 128 + j] += acc * LIN2_SCALE;
    }
}

extern "C" void kernel_launch(void* const* d_in, const int* in_sizes, int n_in,
                              void* d_out, int out_size, void* d_ws, size_t ws_size,
                              hipStream_t stream) {
    const float* nf    = (const float*)d_in[0];
    const float* attrs = (const float*)d_in[1];
    const float* eattr = (const float*)d_in[2];
    const float* ee    = (const float*)d_in[3];
    const int*   eidx  = (const int*)d_in[4];
    const float* l1w0  = (const float*)d_in[5];
    const float* l1w1  = (const float*)d_in[6];
    const float* w0    = (const float*)d_in[7];
    const float* w1    = (const float*)d_in[8];
    const float* l2w0  = (const float*)d_in[9];
    const float* l2w1  = (const float*)d_in[10];
    const float* scw0  = (const float*)d_in[11];
    const float* scw1  = (const float*)d_in[12];

    int N = in_sizes[0] / 128;
    int E = in_sizes[3] / 8;

    // ws layout (keep 8B alignment for float2 w1p)
    float* h4   = (float*)d_ws;                  // N*128 floats
    float* w1p  = h4 + (size_t)N * 128;          // 8192 floats
    int*   cnt  = (int*)(w1p + 8192);            // N
    int*   off  = cnt + N;                       // N+1
    int*   cur  = off + N + 1;                   // N
    int*   order= cur + N;                       // E

    zero_int<<<(N + 255) / 256, 256, 0, stream>>>(cnt, N);
    prep_w1p<<<16, 256, 0, stream>>>(w1, w1p);
    hist_kernel<<<(E + 255) / 256, 256, 0, stream>>>(eidx, cnt, E);
    scan_kernel<<<1, 1024, 0, stream>>>(cnt, off, cur, N);
    scatter_kernel<<<(E + 255) / 256, 256, 0, stream>>>(eidx, cur, order, E);
    node_kernel<<<N, 128, 0, stream>>>(nf, attrs, l1w0, l1w1, scw0, scw1, h4, (float*)d_out);
    gather_kernel<<<N, 64, 0, stream>>>(ee, (const float4*)eattr, eidx, order, off,
                                        w0, (const float2*)w1p, (const float4*)h4,
                                        l2w0, l2w1, (float*)d_out, E);
}